// Round 4
// baseline (260.014 us; speedup 1.0000x reference)
//
#include <hip/hip_runtime.h>

// SDPA causal flash-attention fwd, fp32 in/out, bf16 MFMA compute.
// B=2, S=4096, NH=16, HD=64, input layout (B,S,NH,HD).
// Round 10: tile reshape BM 128->256, 8 waves (512 thr), AITER-style
// ts_qo=256/ts_kv=64. LDS stays 32KB (Q in regs; K/V tiles unchanged)
// -> halves block-iters, halves K/V L2 traffic per FLOP, halves
// barrier-drain events, occupancy ceiling 11->16 waves/CU. Per-wave
// inner work unchanged. + persistent vzero C-operand (kills 32 sacc
// zero-init movs/iter). Keeps R9 wins: permlane32_swap, dot2 l-sum,
// shfl l-broadcast, setprio, launch_bounds that don't squeeze VGPR.

constexpr int BATCH  = 2;
constexpr int SEQ    = 4096;
constexpr int NHEADS = 16;
constexpr int HDIM   = 64;
constexpr int ROWSTR = NHEADS * HDIM;   // 1024 elems between s-rows (native)
constexpr int BM     = 256;  // q rows per block (32 per wave, 8 waves)
constexpr int BN     = 64;   // k cols per tile
constexpr int QTILES = SEQ / BM;        // 16
constexpr int BH     = BATCH * NHEADS;  // 32

typedef __attribute__((ext_vector_type(8)))  short v8s;   // 8 bf16 (MFMA A/B frag)
typedef __attribute__((ext_vector_type(16))) float v16f;  // 32x32 MFMA C/D frag
typedef __attribute__((ext_vector_type(4)))  unsigned int v4u;
typedef __attribute__((ext_vector_type(2)))  unsigned int v2u;
typedef __attribute__((ext_vector_type(2)))  __bf16 v2bf;

__device__ __forceinline__ unsigned pkbf(float a, float b) {  // pack 2 bf16 RNE
#if __has_builtin(__builtin_amdgcn_cvt_pk_bf16_f32)
    return __builtin_bit_cast(unsigned, __builtin_amdgcn_cvt_pk_bf16_f32(a, b));
#else
    unsigned ua = __float_as_uint(a); ua += 0x7FFFu + ((ua >> 16) & 1u);
    unsigned ub = __float_as_uint(b); ub += 0x7FFFu + ((ub >> 16) & 1u);
    return (ua >> 16) | (ub & 0xFFFF0000u);
#endif
}

__device__ __forceinline__ int fswz(int r) { return (r & 7) ^ ((r >> 3) & 3); }

__device__ __forceinline__ void async16(const unsigned short* g, unsigned short* l) {
    __builtin_amdgcn_global_load_lds(
        (const __attribute__((address_space(1))) unsigned int*)g,
        (__attribute__((address_space(3))) unsigned int*)l, 16, 0, 0);
}

// ---------------- prep: K streaming convert + V tiled transpose ------------
// kb: bf16, native flat layout (B,S,NH,HD). vt: bf16 [bh][hd][s] (plain).
// Grid: 2048 blocks x 256 threads.
//   blocks 0..1023   : K fp32->bf16 streaming, 2048 float4 each (8/thread)
//   blocks 1024..2047: V transpose tile = (b, h, 128 s-rows), 16.9KB LDS
__global__ __launch_bounds__(256, 4)
void prep(const float* __restrict__ kf, const float* __restrict__ vf,
          unsigned short* __restrict__ kb, unsigned short* __restrict__ vt)
{
    __shared__ unsigned int lds[128 * 33];   // +1 u32 row pad: conflict-free
    const int tid = threadIdx.x;
    const int blk = (int)blockIdx.x;

    if (blk < 1024) {
        // ---- K: pure streaming fp32 -> bf16, layout unchanged ----
        const float4* src = (const float4*)kf + (size_t)blk * 2048;
        unsigned int* dst = (unsigned int*)kb + (size_t)blk * 4096;
        #pragma unroll
        for (int i = 0; i < 8; ++i) {
            const int n = i * 256 + tid;
            float4 f = src[n];
            *(v2u*)(dst + (size_t)n * 2) = (v2u){pkbf(f.x, f.y), pkbf(f.z, f.w)};
        }
        return;
    }

    // ---- V: one (b, h) head, 128 s-rows -> vt[bh][hd][s] ----
    const int t  = blk - 1024;
    const int b  = t >> 9;             // 0..1
    const int h  = (t >> 5) & 15;      // 0..15
    const int s0 = (t & 31) * 128;     // 0..3968

    {   // store phase: iter i covers 16 s-rows; 16 lanes x 256B per row
        const float4* vff = (const float4*)vf + (size_t)b * SEQ * 256;
        const int c2 = (tid & 15) * 2;           // u32 col pair (hd/2)
        #pragma unroll
        for (int i = 0; i < 8; ++i) {
            const int srow = i * 16 + (tid >> 4);
            float4 f = vff[(size_t)(s0 + srow) * 256 + h * 16 + (tid & 15)];
            lds[srow * 33 + c2]     = pkbf(f.x, f.y);   // hd 2c,2c+1
            lds[srow * 33 + c2 + 1] = pkbf(f.z, f.w);
        }
    }
    __syncthreads();
    {   // read phase: wave w owns s-chunk w*32; lane = hd row; 64B/lane out
        const int w    = tid >> 6;
        const int lane = tid & 63;
        const int sh   = (lane & 1) * 16;
        const unsigned int* lcol = &lds[w * 32 * 33 + (lane >> 1)];
        unsigned int out[16];
        #pragma unroll
        for (int j = 0; j < 16; ++j) {           // s-pair {2j, 2j+1}
            const unsigned a = lcol[(2 * j)     * 33];
            const unsigned c = lcol[(2 * j + 1) * 33];
            out[j] = ((a >> sh) & 0xFFFFu) | (((c >> sh) & 0xFFFFu) << 16);
        }
        unsigned int* dst = (unsigned int*)vt
            + ((size_t)((b * NHEADS + h) * HDIM + lane)) * (SEQ / 2)
            + ((s0 + w * 32) >> 1);
        #pragma unroll
        for (int j = 0; j < 4; ++j)
            *(v4u*)(dst + 4 * j) = (v4u){out[4*j], out[4*j+1], out[4*j+2], out[4*j+3]};
    }
}

// ---------------- main flash-attention kernel -------------------------------
// 512 threads = 8 waves; wave w owns q rows [wave*32, wave*32+32) of the
// 256-row q tile. K/V tiles 64x64 double-buffered, 32KB LDS total.
__global__ __launch_bounds__(512, 2)
void fa_fwd(const float* __restrict__ qf, const unsigned short* __restrict__ kb,
            const unsigned short* __restrict__ vt, float* __restrict__ og)
{
    __shared__ __align__(16) unsigned short k_s[2][64 * 64];  // [kcol s][hd], swizzled
    __shared__ __align__(16) unsigned short v_s[2][64 * 64];  // [hd][kcol s], swizzled

    const int tid  = threadIdx.x;
    const int wave = tid >> 6;           // 0..7
    const int lane = tid & 63;
    const int hh   = lane >> 5;          // half-wave
    const int l32  = lane & 31;

    const int n  = (int)blockIdx.x;
    const int qtile = QTILES - 1 - (n >> 5);   // longest first; bh fastest (XCD spread)
    const int bh = n & 31;
    const int b = bh >> 4, h = bh & 15;
    const int qbase = qtile * BM;
    const int jmax  = 4 * qtile + 4;

    // DMA lane mapping: wave w stages rows [w*8, w*8+8) of each 64-row tile.
    // dest (row = w*8 + (lane>>3), slot lane&7); source data-group =
    // (lane&7) ^ fswz(row) = (lane&7) ^ (lane>>3) ^ (wave&3).
    const int lrow  = lane >> 3;
    const int lcol8 = (lane & 7) ^ lrow ^ (wave & 3);
    // frag-read group xor term: fswz(mt*32 + l32) = (l32&7) ^ ((l32>>3)&3)
    const int fx = (l32 & 7) ^ ((l32 >> 3) & 3);

    // ---- stage Q (256x64, scaled, fp32 -> bf16) once through all 4 buffers ----
    {
        const int krow = tid >> 2;                 // 0..127
        const int kc   = (tid & 3) * 16;
        const float sc = 0.125f * 1.44269504088896340736f;
        #pragma unroll
        for (int half = 0; half < 2; ++half) {
            const int row = half * 128 + krow;     // 0..255
            const int rr  = row & 63;
            const int sg0 = (2 * (tid & 3))     ^ fswz(rr);
            const int sg1 = (2 * (tid & 3) + 1) ^ fswz(rr);
            const float4* src = (const float4*)(qf +
                ((size_t)((b * SEQ + qbase + row) * NHEADS + h)) * HDIM + kc);
            float4 f0 = src[0], f1 = src[1], f2 = src[2], f3 = src[3];
            const int sel = row >> 6;              // 0..3
            unsigned short* dst = (sel == 0) ? &k_s[0][rr * 64]
                                : (sel == 1) ? &k_s[1][rr * 64]
                                : (sel == 2) ? &v_s[0][rr * 64]
                                             : &v_s[1][rr * 64];
            *(v4u*)&dst[sg0 * 8] = (v4u){pkbf(f0.x*sc, f0.y*sc), pkbf(f0.z*sc, f0.w*sc),
                                         pkbf(f1.x*sc, f1.y*sc), pkbf(f1.z*sc, f1.w*sc)};
            *(v4u*)&dst[sg1 * 8] = (v4u){pkbf(f2.x*sc, f2.y*sc), pkbf(f2.z*sc, f2.w*sc),
                                         pkbf(f3.x*sc, f3.y*sc), pkbf(f3.z*sc, f3.w*sc)};
        }
    }
    __syncthreads();
    v8s bq[4];   // lane holds Q[q = wave*32+l32][hd = 16c + hh*8 + j]
    {
        const int R   = wave * 32 + l32;           // 0..255
        const int sel = wave >> 1;                 // == R>>6, wave-uniform
        const int rr  = R & 63;
        const unsigned short* qb = (sel == 0) ? &k_s[0][0]
                                 : (sel == 1) ? &k_s[1][0]
                                 : (sel == 2) ? &v_s[0][0]
                                              : &v_s[1][0];
        #pragma unroll
        for (int c = 0; c < 4; ++c)
            bq[c] = *(const v8s*)&qb[rr * 64 + (((2*c + hh) ^ fswz(rr)) * 8)];
    }
    __syncthreads();   // Q reads done before tile-0 DMA overwrites buffers

    const unsigned short* kgb = kb + (size_t)b * SEQ * ROWSTR + (size_t)h * HDIM;
    const unsigned short* vgb = vt + (size_t)bh * HDIM * SEQ;

    // ---- K/V tile 0: each wave stages its 8 rows of K and of V ----
    {
        const int rbase = wave * 8;
        async16(kgb + (size_t)(rbase + lrow) * ROWSTR + lcol8 * 8, &k_s[0][rbase * 64]);
        async16(vgb + (size_t)(rbase + lrow) * SEQ    + lcol8 * 8, &v_s[0][rbase * 64]);
    }

    const v16f vzero = (v16f)(0.f);      // persistent C=0 operand
    v16f o_acc[2];
    o_acc[0] = (v16f)(0.f); o_acc[1] = (v16f)(0.f);
    float l_lane = 0.f;
    const int q_abs = qbase + wave * 32 + l32;

#if __has_builtin(__builtin_amdgcn_fdot2_f32_bf16)
    const v2bf ones2 = __builtin_bit_cast(v2bf, 0x3F803F80u);   // {1.0bf, 1.0bf}
#endif

    for (int jt = 0; jt < jmax; ++jt) {
        const int buf = jt & 1;
        __syncthreads();   // implicit vmcnt(0): tile jt resident; prior buf reads done

        if (jt + 1 < jmax) {   // prefetch jt+1; in flight across this iteration
            const int nb  = (jt + 1) & 1;
            const int kb2 = (jt + 1) * BN;
            const int rbase = wave * 8;
            async16(kgb + (size_t)(kb2 + rbase + lrow) * ROWSTR + lcol8 * 8, &k_s[nb][rbase * 64]);
            async16(vgb + (size_t)(rbase + lrow) * SEQ + kb2    + lcol8 * 8, &v_s[nb][rbase * 64]);
        }

        // ---- S^T = K Q^T : M=kcol(64, 2 tiles), N=q(32), K=hd(64, 4 chunks) ----
        v16f sacc[2];
        __builtin_amdgcn_s_setprio(1);
        #pragma unroll
        for (int mt = 0; mt < 2; ++mt) {
            const int r = mt * 32 + l32;   // k-col row in k_s
            {
                v8s ak = *(const v8s*)&k_s[buf][r * 64 + ((hh ^ fx) * 8)];
                sacc[mt] = __builtin_amdgcn_mfma_f32_32x32x16_bf16(ak, bq[0], vzero, 0, 0, 0);
            }
            #pragma unroll
            for (int c = 1; c < 4; ++c) {
                v8s ak = *(const v8s*)&k_s[buf][r * 64 + (((2*c + hh) ^ fx) * 8)];
                sacc[mt] = __builtin_amdgcn_mfma_f32_32x32x16_bf16(ak, bq[c], sacc[mt], 0, 0, 0);
            }
        }
        __builtin_amdgcn_s_setprio(0);

        // ---- p = exp2(s), causal mask (last 4 tiles), pack+exchange, l-sum ----
        const bool masked = (jt >= jmax - 4);
        v8s pf[4];
        #pragma unroll
        for (int mt = 0; mt < 2; ++mt) {
            #pragma unroll
            for (int r = 0; r < 16; ++r) {
                float pv = __builtin_amdgcn_exp2f(sacc[mt][r]);
                if (masked) {
                    const int k_abs = jt * 64 + mt * 32 + (r & 3) + 8 * (r >> 2) + 4 * hh;
                    pv = (k_abs > q_abs) ? 0.f : pv;
                }
                sacc[mt][r] = pv;
#if !__has_builtin(__builtin_amdgcn_fdot2_f32_bf16)
                l_lane += pv;
#endif
            }
            #pragma unroll
            for (int cc = 0; cc < 2; ++cc) {
                const unsigned lo0 = pkbf(sacc[mt][8*cc+0], sacc[mt][8*cc+1]);
                const unsigned lo1 = pkbf(sacc[mt][8*cc+2], sacc[mt][8*cc+3]);
                const unsigned hi0 = pkbf(sacc[mt][8*cc+4], sacc[mt][8*cc+5]);
                const unsigned hi1 = pkbf(sacc[mt][8*cc+6], sacc[mt][8*cc+7]);
#if __has_builtin(__builtin_amdgcn_fdot2_f32_bf16)
                // l-sum on packed bf16 P: matches the bf16 numerator rounding.
                l_lane = __builtin_amdgcn_fdot2_f32_bf16(__builtin_bit_cast(v2bf, lo0), ones2, l_lane, false);
                l_lane = __builtin_amdgcn_fdot2_f32_bf16(__builtin_bit_cast(v2bf, lo1), ones2, l_lane, false);
                l_lane = __builtin_amdgcn_fdot2_f32_bf16(__builtin_bit_cast(v2bf, hi0), ones2, l_lane, false);
                l_lane = __builtin_amdgcn_fdot2_f32_bf16(__builtin_bit_cast(v2bf, hi1), ones2, l_lane, false);
#endif
#if __has_builtin(__builtin_amdgcn_permlane32_swap)
                auto r0 = __builtin_amdgcn_permlane32_swap(lo0, hi0, false, false);
                auto r1 = __builtin_amdgcn_permlane32_swap(lo1, hi1, false, false);
                pf[mt*2 + cc] = __builtin_bit_cast(v8s, (v4u){r0[0], r1[0], r0[1], r1[1]});
#else
                const unsigned s0 = hh ? lo0 : hi0;   // send interleaved run
                const unsigned s1 = hh ? lo1 : hi1;
                const unsigned t0 = (unsigned)__shfl_xor((int)s0, 32, 64);
                const unsigned t1 = (unsigned)__shfl_xor((int)s1, 32, 64);
                v4u w;
                w.x = hh ? t0 : lo0;
                w.y = hh ? t1 : lo1;
                w.z = hh ? hi0 : t0;
                w.w = hh ? hi1 : t1;
                pf[mt*2 + cc] = __builtin_bit_cast(v8s, w);
#endif
            }
        }

        // ---- O += P V : M=q(32), N=hd(64, 2 tiles), K=kcol(64, 4 chunks) ----
        __builtin_amdgcn_s_setprio(1);
        #pragma unroll
        for (int nt = 0; nt < 2; ++nt) {
            const int r = nt * 32 + l32;   // hd row in v_s
            #pragma unroll
            for (int c = 0; c < 4; ++c) {
                v8s bv = *(const v8s*)&v_s[buf][r * 64 + (((2*c + hh) ^ fx) * 8)];
                o_acc[nt] = __builtin_amdgcn_mfma_f32_32x32x16_bf16(pf[c], bv, o_acc[nt], 0, 0, 0);
            }
        }
        __builtin_amdgcn_s_setprio(0);
    }

    // ---- epilogue: l via wave shuffles (no LDS, no extra barrier) ----
    // lt = full row-sum for q = wave*32 + l32, valid in all 64 lanes.
    const float lt = l_lane + __shfl_xor(l_lane, 32);

    #pragma unroll
    for (int r = 0; r < 16; ++r) {
        const int q_local = (r & 3) + 8 * (r >> 2) + 4 * hh;
        const float inv_l = 1.0f / __shfl(lt, q_local, 32);   // within 32-lane group
        const int qrow = qbase + wave * 32 + q_local;
        float* dst = og + ((size_t)((b * SEQ + qrow) * NHEADS + h)) * HDIM + l32;
        dst[0]  = o_acc[0][r] * inv_l;
        dst[32] = o_acc[1][r] * inv_l;
    }
}

extern "C" void kernel_launch(void* const* d_in, const int* in_sizes, int n_in,
                              void* d_out, int out_size, void* d_ws, size_t ws_size,
                              hipStream_t stream) {
    const float* q = (const float*)d_in[0];
    const float* k = (const float*)d_in[1];
    const float* v = (const float*)d_in[2];
    float* out = (float*)d_out;

    const size_t TEN = (size_t)BATCH * NHEADS * SEQ * HDIM;  // 8.39M elems
    unsigned short* kbuf = (unsigned short*)d_ws;
    unsigned short* vbuf = kbuf + TEN;

    prep<<<2048, 256, 0, stream>>>(k, v, kbuf, vbuf);
    fa_fwd<<<QTILES * BH, 512, 0, stream>>>(q, kbuf, vbuf, out);
}

// Round 5
// 246.869 us; speedup vs baseline: 1.0532x; 1.0532x over previous
//
#include <hip/hip_runtime.h>

// SDPA causal flash-attention fwd, fp32 in/out, bf16 MFMA compute.
// B=2, S=4096, NH=16, HD=64, input layout (B,S,NH,HD).
// Round 11: revert R10 reshape (2 blocks/CU + 8-wave lockstep regressed;
// back to BM=128/4 waves/1024 blocks). Structural change: 3-deep K/V LDS
// pipeline (48KB) with counted vmcnt -- issue tile jt+2 during iter jt,
// end iter with s_waitcnt vmcnt(4) + raw s_barrier (tile jt+2's 4 loads
// stay IN FLIGHT across the barrier; never drain to 0 in steady state).
// This replaces __syncthreads' vmcnt(0) full drain (T3/T4, the measured
// +28-73% GEMM lever). Keeps R9 wins (permlane32_swap, dot2 l-sum, shfl
// l-broadcast, setprio) + R10's persistent vzero C-operand.

constexpr int BATCH  = 2;
constexpr int SEQ    = 4096;
constexpr int NHEADS = 16;
constexpr int HDIM   = 64;
constexpr int ROWSTR = NHEADS * HDIM;   // 1024 elems between s-rows (native)
constexpr int BM     = 128;  // q rows per block (32 per wave, 4 waves)
constexpr int BN     = 64;   // k cols per tile
constexpr int QTILES = SEQ / BM;        // 32
constexpr int BH     = BATCH * NHEADS;  // 32

typedef __attribute__((ext_vector_type(8)))  short v8s;   // 8 bf16 (MFMA A/B frag)
typedef __attribute__((ext_vector_type(16))) float v16f;  // 32x32 MFMA C/D frag
typedef __attribute__((ext_vector_type(4)))  unsigned int v4u;
typedef __attribute__((ext_vector_type(2)))  unsigned int v2u;
typedef __attribute__((ext_vector_type(2)))  __bf16 v2bf;

__device__ __forceinline__ unsigned pkbf(float a, float b) {  // pack 2 bf16 RNE
#if __has_builtin(__builtin_amdgcn_cvt_pk_bf16_f32)
    return __builtin_bit_cast(unsigned, __builtin_amdgcn_cvt_pk_bf16_f32(a, b));
#else
    unsigned ua = __float_as_uint(a); ua += 0x7FFFu + ((ua >> 16) & 1u);
    unsigned ub = __float_as_uint(b); ub += 0x7FFFu + ((ub >> 16) & 1u);
    return (ua >> 16) | (ub & 0xFFFF0000u);
#endif
}

__device__ __forceinline__ int fswz(int r) { return (r & 7) ^ ((r >> 3) & 3); }

__device__ __forceinline__ void async16(const unsigned short* g, unsigned short* l) {
    __builtin_amdgcn_global_load_lds(
        (const __attribute__((address_space(1))) unsigned int*)g,
        (__attribute__((address_space(3))) unsigned int*)l, 16, 0, 0);
}

// ---------------- prep: K streaming convert + V tiled transpose ------------
// kb: bf16, native flat layout (B,S,NH,HD). vt: bf16 [bh][hd][s] (plain).
// Grid: 2048 blocks x 256 threads.
//   blocks 0..1023   : K fp32->bf16 streaming, 2048 float4 each (8/thread)
//   blocks 1024..2047: V transpose tile = (b, h, 128 s-rows), 16.9KB LDS
__global__ __launch_bounds__(256, 4)
void prep(const float* __restrict__ kf, const float* __restrict__ vf,
          unsigned short* __restrict__ kb, unsigned short* __restrict__ vt)
{
    __shared__ unsigned int lds[128 * 33];   // +1 u32 row pad: conflict-free
    const int tid = threadIdx.x;
    const int blk = (int)blockIdx.x;

    if (blk < 1024) {
        // ---- K: pure streaming fp32 -> bf16, layout unchanged ----
        const float4* src = (const float4*)kf + (size_t)blk * 2048;
        unsigned int* dst = (unsigned int*)kb + (size_t)blk * 4096;
        #pragma unroll
        for (int i = 0; i < 8; ++i) {
            const int n = i * 256 + tid;
            float4 f = src[n];
            *(v2u*)(dst + (size_t)n * 2) = (v2u){pkbf(f.x, f.y), pkbf(f.z, f.w)};
        }
        return;
    }

    // ---- V: one (b, h) head, 128 s-rows -> vt[bh][hd][s] ----
    const int t  = blk - 1024;
    const int b  = t >> 9;             // 0..1
    const int h  = (t >> 5) & 15;      // 0..15
    const int s0 = (t & 31) * 128;     // 0..3968

    {   // store phase: iter i covers 16 s-rows; 16 lanes x 256B per row
        const float4* vff = (const float4*)vf + (size_t)b * SEQ * 256;
        const int c2 = (tid & 15) * 2;           // u32 col pair (hd/2)
        #pragma unroll
        for (int i = 0; i < 8; ++i) {
            const int srow = i * 16 + (tid >> 4);
            float4 f = vff[(size_t)(s0 + srow) * 256 + h * 16 + (tid & 15)];
            lds[srow * 33 + c2]     = pkbf(f.x, f.y);   // hd 2c,2c+1
            lds[srow * 33 + c2 + 1] = pkbf(f.z, f.w);
        }
    }
    __syncthreads();
    {   // read phase: wave w owns s-chunk w*32; lane = hd row; 64B/lane out
        const int w    = tid >> 6;
        const int lane = tid & 63;
        const int sh   = (lane & 1) * 16;
        const unsigned int* lcol = &lds[w * 32 * 33 + (lane >> 1)];
        unsigned int out[16];
        #pragma unroll
        for (int j = 0; j < 16; ++j) {           // s-pair {2j, 2j+1}
            const unsigned a = lcol[(2 * j)     * 33];
            const unsigned c = lcol[(2 * j + 1) * 33];
            out[j] = ((a >> sh) & 0xFFFFu) | (((c >> sh) & 0xFFFFu) << 16);
        }
        unsigned int* dst = (unsigned int*)vt
            + ((size_t)((b * NHEADS + h) * HDIM + lane)) * (SEQ / 2)
            + ((s0 + w * 32) >> 1);
        #pragma unroll
        for (int j = 0; j < 4; ++j)
            *(v4u*)(dst + 4 * j) = (v4u){out[4*j], out[4*j+1], out[4*j+2], out[4*j+3]};
    }
}

// ---------------- main flash-attention kernel -------------------------------
__global__ __launch_bounds__(256, 4)
void fa_fwd(const float* __restrict__ qf, const unsigned short* __restrict__ kb,
            const unsigned short* __restrict__ vt, float* __restrict__ og)
{
    __shared__ __align__(16) unsigned short k_s[3][64 * 64];  // [kcol s][hd], swizzled
    __shared__ __align__(16) unsigned short v_s[3][64 * 64];  // [hd][kcol s], swizzled
    // LDS total = 48 KB -> 3 blocks/CU; 3-deep tile pipeline.

    const int tid  = threadIdx.x;
    const int wave = tid >> 6;
    const int lane = tid & 63;
    const int hh   = lane >> 5;          // half-wave
    const int l32  = lane & 31;

    const int n  = (int)blockIdx.x;
    const int qtile = QTILES - 1 - (n >> 5);   // longest first; bh fastest (XCD spread)
    const int bh = n & 31;
    const int b = bh >> 4, h = bh & 15;
    const int qbase = qtile * BM;
    const int jmax  = 2 * qtile + 2;           // >= 2 always

    // DMA lane mapping: lane -> (local row = rbase + (lane>>3), slot lane&7);
    // source data-group = (lane&7) ^ fswz(local row) = (lane&7) ^ (lane>>3) ^ wave
    const int lrow  = lane >> 3;
    const int lcol8 = (lane & 7) ^ lrow ^ wave;
    // frag-read group xor term: fswz(mt*32 + l32) = (l32&7) ^ ((l32>>3)&3)
    const int fx = (l32 & 7) ^ ((l32 >> 3) & 3);

    // ---- stage Q (128x64, scaled, fp32 -> bf16) once through buf0 ----
    {
        const int krow = tid >> 2;                 // 0..63
        const int kc   = (tid & 3) * 16;
        const int sg0  = (2 * (tid & 3))     ^ fswz(krow);
        const int sg1  = (2 * (tid & 3) + 1) ^ fswz(krow);
        const float sc = 0.125f * 1.44269504088896340736f;
        #pragma unroll
        for (int half = 0; half < 2; ++half) {
            const float4* src = (const float4*)(qf +
                ((size_t)((b * SEQ + qbase + half * 64 + krow) * NHEADS + h)) * HDIM + kc);
            float4 f0 = src[0], f1 = src[1], f2 = src[2], f3 = src[3];
            unsigned short* dst = half ? &v_s[0][krow * 64] : &k_s[0][krow * 64];
            *(v4u*)&dst[sg0 * 8] = (v4u){pkbf(f0.x*sc, f0.y*sc), pkbf(f0.z*sc, f0.w*sc),
                                         pkbf(f1.x*sc, f1.y*sc), pkbf(f1.z*sc, f1.w*sc)};
            *(v4u*)&dst[sg1 * 8] = (v4u){pkbf(f2.x*sc, f2.y*sc), pkbf(f2.z*sc, f2.w*sc),
                                         pkbf(f3.x*sc, f3.y*sc), pkbf(f3.z*sc, f3.w*sc)};
        }
    }
    __syncthreads();
    v8s bq[4];   // lane holds Q[q = wave*32+l32][hd = 16c + hh*8 + j]
    {
        const int R = wave * 32 + l32;
        const unsigned short* qrow = (R < 64) ? &k_s[0][R * 64] : &v_s[0][(R - 64) * 64];
        #pragma unroll
        for (int c = 0; c < 4; ++c)
            bq[c] = *(const v8s*)&qrow[(((2*c + hh) ^ fswz(R & 63)) * 8)];
    }
    __syncthreads();   // Q reads done before tile-0 DMA overwrites buf0; vmcnt=0 here

    const unsigned short* kgb = kb + (size_t)b * SEQ * ROWSTR + (size_t)h * HDIM;
    const unsigned short* vgb = vt + (size_t)bh * HDIM * SEQ;

    // ---- prologue: stage tiles 0 and 1 (8 loads/wave, issue order t0 then t1) ----
    #pragma unroll
    for (int t = 0; t < 2; ++t) {
        const int kb2 = t * BN;
        #pragma unroll
        for (int i = 0; i < 2; ++i) {
            const int rbase = i * 32 + wave * 8;
            async16(kgb + (size_t)(kb2 + rbase + lrow) * ROWSTR + lcol8 * 8, &k_s[t][rbase * 64]);
            async16(vgb + (size_t)(rbase + lrow) * SEQ + kb2    + lcol8 * 8, &v_s[t][rbase * 64]);
        }
    }
    asm volatile("s_waitcnt vmcnt(4)" ::: "memory");   // tile 0's 4 loads done
    __builtin_amdgcn_s_barrier();                      // all waves' tile-0 loads done
    __builtin_amdgcn_sched_barrier(0);

    const v16f vzero = (v16f)(0.f);      // persistent C=0 operand
    v16f o_acc[2];
    o_acc[0] = (v16f)(0.f); o_acc[1] = (v16f)(0.f);
    float l_lane = 0.f;
    const int q_abs = qbase + wave * 32 + l32;

#if __has_builtin(__builtin_amdgcn_fdot2_f32_bf16)
    const v2bf ones2 = __builtin_bit_cast(v2bf, 0x3F803F80u);   // {1.0bf, 1.0bf}
#endif

    int cur = 0;                         // buffer of tile jt (= jt % 3)
    for (int jt = 0; jt < jmax; ++jt) {
        // ---- issue DMA for tile jt+2 into buf (jt+2)%3 (stays in flight
        //      across this iteration's end barrier: counted vmcnt below) ----
        if (jt + 2 < jmax) {
            int pf = cur + 2; if (pf >= 3) pf -= 3;
            const int kb2 = (jt + 2) * BN;
            #pragma unroll
            for (int i = 0; i < 2; ++i) {
                const int rbase = i * 32 + wave * 8;
                async16(kgb + (size_t)(kb2 + rbase + lrow) * ROWSTR + lcol8 * 8, &k_s[pf][rbase * 64]);
                async16(vgb + (size_t)(rbase + lrow) * SEQ + kb2    + lcol8 * 8, &v_s[pf][rbase * 64]);
            }
        }

        // ---- S^T = K Q^T : M=kcol(64, 2 tiles), N=q(32), K=hd(64, 4 chunks) ----
        const unsigned short* ksb = &k_s[cur][0];
        const unsigned short* vsb = &v_s[cur][0];
        v16f sacc[2];
        __builtin_amdgcn_s_setprio(1);
        #pragma unroll
        for (int mt = 0; mt < 2; ++mt) {
            const int r = mt * 32 + l32;   // k-col row in k_s
            {
                v8s ak = *(const v8s*)&ksb[r * 64 + ((hh ^ fx) * 8)];
                sacc[mt] = __builtin_amdgcn_mfma_f32_32x32x16_bf16(ak, bq[0], vzero, 0, 0, 0);
            }
            #pragma unroll
            for (int c = 1; c < 4; ++c) {
                v8s ak = *(const v8s*)&ksb[r * 64 + (((2*c + hh) ^ fx) * 8)];
                sacc[mt] = __builtin_amdgcn_mfma_f32_32x32x16_bf16(ak, bq[c], sacc[mt], 0, 0, 0);
            }
        }
        __builtin_amdgcn_s_setprio(0);

        // ---- p = exp2(s), causal mask (last 2 tiles), pack+exchange, l-sum ----
        const bool masked = (jt >= jmax - 2);
        v8s pf4[4];
        #pragma unroll
        for (int mt = 0; mt < 2; ++mt) {
            #pragma unroll
            for (int r = 0; r < 16; ++r) {
                float pv = __builtin_amdgcn_exp2f(sacc[mt][r]);
                if (masked) {
                    const int k_abs = jt * 64 + mt * 32 + (r & 3) + 8 * (r >> 2) + 4 * hh;
                    pv = (k_abs > q_abs) ? 0.f : pv;
                }
                sacc[mt][r] = pv;
#if !__has_builtin(__builtin_amdgcn_fdot2_f32_bf16)
                l_lane += pv;
#endif
            }
            #pragma unroll
            for (int cc = 0; cc < 2; ++cc) {
                const unsigned lo0 = pkbf(sacc[mt][8*cc+0], sacc[mt][8*cc+1]);
                const unsigned lo1 = pkbf(sacc[mt][8*cc+2], sacc[mt][8*cc+3]);
                const unsigned hi0 = pkbf(sacc[mt][8*cc+4], sacc[mt][8*cc+5]);
                const unsigned hi1 = pkbf(sacc[mt][8*cc+6], sacc[mt][8*cc+7]);
#if __has_builtin(__builtin_amdgcn_fdot2_f32_bf16)
                // l-sum on packed bf16 P: matches the bf16 numerator rounding.
                l_lane = __builtin_amdgcn_fdot2_f32_bf16(__builtin_bit_cast(v2bf, lo0), ones2, l_lane, false);
                l_lane = __builtin_amdgcn_fdot2_f32_bf16(__builtin_bit_cast(v2bf, lo1), ones2, l_lane, false);
                l_lane = __builtin_amdgcn_fdot2_f32_bf16(__builtin_bit_cast(v2bf, hi0), ones2, l_lane, false);
                l_lane = __builtin_amdgcn_fdot2_f32_bf16(__builtin_bit_cast(v2bf, hi1), ones2, l_lane, false);
#endif
#if __has_builtin(__builtin_amdgcn_permlane32_swap)
                auto r0 = __builtin_amdgcn_permlane32_swap(lo0, hi0, false, false);
                auto r1 = __builtin_amdgcn_permlane32_swap(lo1, hi1, false, false);
                pf4[mt*2 + cc] = __builtin_bit_cast(v8s, (v4u){r0[0], r1[0], r0[1], r1[1]});
#else
                const unsigned s0 = hh ? lo0 : hi0;   // send interleaved run
                const unsigned s1 = hh ? lo1 : hi1;
                const unsigned t0 = (unsigned)__shfl_xor((int)s0, 32, 64);
                const unsigned t1 = (unsigned)__shfl_xor((int)s1, 32, 64);
                v4u w;
                w.x = hh ? t0 : lo0;
                w.y = hh ? t1 : lo1;
                w.z = hh ? hi0 : t0;
                w.w = hh ? hi1 : t1;
                pf4[mt*2 + cc] = __builtin_bit_cast(v8s, w);
#endif
            }
        }

        // ---- O += P V : M=q(32), N=hd(64, 2 tiles), K=kcol(64, 4 chunks) ----
        __builtin_amdgcn_s_setprio(1);
        #pragma unroll
        for (int nt = 0; nt < 2; ++nt) {
            const int r = nt * 32 + l32;   // hd row in v_s
            #pragma unroll
            for (int c = 0; c < 4; ++c) {
                v8s bv = *(const v8s*)&vsb[r * 64 + (((2*c + hh) ^ fx) * 8)];
                o_acc[nt] = __builtin_amdgcn_mfma_f32_32x32x16_bf16(pf4[c], bv, o_acc[nt], 0, 0, 0);
            }
        }
        __builtin_amdgcn_s_setprio(0);

        // ---- end-of-iter sync: wait ONLY tile jt+1's loads (4), keep jt+2's
        //      4 in flight across the barrier; full drain only at the tail ----
        if (jt + 1 < jmax) {
            if (jt + 2 < jmax) asm volatile("s_waitcnt vmcnt(4)" ::: "memory");
            else               asm volatile("s_waitcnt vmcnt(0)" ::: "memory");
            __builtin_amdgcn_s_barrier();
            __builtin_amdgcn_sched_barrier(0);
        }
        cur = (cur == 2) ? 0 : cur + 1;
    }

    // ---- epilogue: l via wave shuffles (no LDS, no extra barrier) ----
    // lt = full row-sum for q = wave*32 + l32, valid in all 64 lanes.
    const float lt = l_lane + __shfl_xor(l_lane, 32);

    #pragma unroll
    for (int r = 0; r < 16; ++r) {
        const int q_local = (r & 3) + 8 * (r >> 2) + 4 * hh;
        const float inv_l = 1.0f / __shfl(lt, q_local, 32);   // within 32-lane group
        const int qrow = qbase + wave * 32 + q_local;
        float* dst = og + ((size_t)((b * SEQ + qrow) * NHEADS + h)) * HDIM + l32;
        dst[0]  = o_acc[0][r] * inv_l;
        dst[32] = o_acc[1][r] * inv_l;
    }
}

extern "C" void kernel_launch(void* const* d_in, const int* in_sizes, int n_in,
                              void* d_out, int out_size, void* d_ws, size_t ws_size,
                              hipStream_t stream) {
    const float* q = (const float*)d_in[0];
    const float* k = (const float*)d_in[1];
    const float* v = (const float*)d_in[2];
    float* out = (float*)d_out;

    const size_t TEN = (size_t)BATCH * NHEADS * SEQ * HDIM;  // 8.39M elems
    unsigned short* kbuf = (unsigned short*)d_ws;
    unsigned short* vbuf = kbuf + TEN;

    prep<<<2048, 256, 0, stream>>>(k, v, kbuf, vbuf);
    fa_fwd<<<QTILES * BH, 256, 0, stream>>>(q, kbuf, vbuf, out);
}

// Round 6
// 240.926 us; speedup vs baseline: 1.0792x; 1.0247x over previous
//
#include <hip/hip_runtime.h>

// SDPA causal flash-attention fwd, fp32 in/out, bf16 MFMA compute.
// B=2, S=4096, NH=16, HD=64, input layout (B,S,NH,HD).
// Round 12: R9 base (best measured, 141.6us fa_fwd). R11's counted-vmcnt
// falsified the barrier-drain theory (loads have a full iter of cover);
// new theory: intra-iter serial chain QK->exp->PV x 64 iters on the
// longest blocks. Change: mt-phased interleave -- PV chunks c=0,1 depend
// only on exp(mt0), c=2,3 only on exp(mt1), so run exp/pack(mt1) [VALU]
// concurrently with PV(c=0,1) [MFMA] (T15-style overlap, no extra LDS,
// no runtime buffer indexing, still one barrier/iter). + persistent
// vzero C-operand (kills 32 accvgpr zero-inits/iter). Keeps R9 wins:
// permlane32_swap, dot2 l-sum, shfl l-broadcast, setprio on MFMA-only.

constexpr int BATCH  = 2;
constexpr int SEQ    = 4096;
constexpr int NHEADS = 16;
constexpr int HDIM   = 64;
constexpr int ROWSTR = NHEADS * HDIM;   // 1024 elems between s-rows (native)
constexpr int BM     = 128;  // q rows per block (32 per wave, 4 waves)
constexpr int BN     = 64;   // k cols per tile
constexpr int QTILES = SEQ / BM;        // 32
constexpr int BH     = BATCH * NHEADS;  // 32

typedef __attribute__((ext_vector_type(8)))  short v8s;   // 8 bf16 (MFMA A/B frag)
typedef __attribute__((ext_vector_type(16))) float v16f;  // 32x32 MFMA C/D frag
typedef __attribute__((ext_vector_type(4)))  unsigned int v4u;
typedef __attribute__((ext_vector_type(2)))  unsigned int v2u;
typedef __attribute__((ext_vector_type(2)))  __bf16 v2bf;

__device__ __forceinline__ unsigned pkbf(float a, float b) {  // pack 2 bf16 RNE
#if __has_builtin(__builtin_amdgcn_cvt_pk_bf16_f32)
    return __builtin_bit_cast(unsigned, __builtin_amdgcn_cvt_pk_bf16_f32(a, b));
#else
    unsigned ua = __float_as_uint(a); ua += 0x7FFFu + ((ua >> 16) & 1u);
    unsigned ub = __float_as_uint(b); ub += 0x7FFFu + ((ub >> 16) & 1u);
    return (ua >> 16) | (ub & 0xFFFF0000u);
#endif
}

__device__ __forceinline__ int fswz(int r) { return (r & 7) ^ ((r >> 3) & 3); }

__device__ __forceinline__ void async16(const unsigned short* g, unsigned short* l) {
    __builtin_amdgcn_global_load_lds(
        (const __attribute__((address_space(1))) unsigned int*)g,
        (__attribute__((address_space(3))) unsigned int*)l, 16, 0, 0);
}

// ---------------- prep: K streaming convert + V tiled transpose ------------
// kb: bf16, native flat layout (B,S,NH,HD). vt: bf16 [bh][hd][s] (plain).
// Grid: 2048 blocks x 256 threads.
//   blocks 0..1023   : K fp32->bf16 streaming, 2048 float4 each (8/thread)
//   blocks 1024..2047: V transpose tile = (b, h, 128 s-rows), 16.9KB LDS
__global__ __launch_bounds__(256, 4)
void prep(const float* __restrict__ kf, const float* __restrict__ vf,
          unsigned short* __restrict__ kb, unsigned short* __restrict__ vt)
{
    __shared__ unsigned int lds[128 * 33];   // +1 u32 row pad: conflict-free
    const int tid = threadIdx.x;
    const int blk = (int)blockIdx.x;

    if (blk < 1024) {
        // ---- K: pure streaming fp32 -> bf16, layout unchanged ----
        const float4* src = (const float4*)kf + (size_t)blk * 2048;
        unsigned int* dst = (unsigned int*)kb + (size_t)blk * 4096;
        #pragma unroll
        for (int i = 0; i < 8; ++i) {
            const int n = i * 256 + tid;
            float4 f = src[n];
            *(v2u*)(dst + (size_t)n * 2) = (v2u){pkbf(f.x, f.y), pkbf(f.z, f.w)};
        }
        return;
    }

    // ---- V: one (b, h) head, 128 s-rows -> vt[bh][hd][s] ----
    const int t  = blk - 1024;
    const int b  = t >> 9;             // 0..1
    const int h  = (t >> 5) & 15;      // 0..15
    const int s0 = (t & 31) * 128;     // 0..3968

    {   // store phase: iter i covers 16 s-rows; 16 lanes x 256B per row
        const float4* vff = (const float4*)vf + (size_t)b * SEQ * 256;
        const int c2 = (tid & 15) * 2;           // u32 col pair (hd/2)
        #pragma unroll
        for (int i = 0; i < 8; ++i) {
            const int srow = i * 16 + (tid >> 4);
            float4 f = vff[(size_t)(s0 + srow) * 256 + h * 16 + (tid & 15)];
            lds[srow * 33 + c2]     = pkbf(f.x, f.y);   // hd 2c,2c+1
            lds[srow * 33 + c2 + 1] = pkbf(f.z, f.w);
        }
    }
    __syncthreads();
    {   // read phase: wave w owns s-chunk w*32; lane = hd row; 64B/lane out
        const int w    = tid >> 6;
        const int lane = tid & 63;
        const int sh   = (lane & 1) * 16;
        const unsigned int* lcol = &lds[w * 32 * 33 + (lane >> 1)];
        unsigned int out[16];
        #pragma unroll
        for (int j = 0; j < 16; ++j) {           // s-pair {2j, 2j+1}
            const unsigned a = lcol[(2 * j)     * 33];
            const unsigned c = lcol[(2 * j + 1) * 33];
            out[j] = ((a >> sh) & 0xFFFFu) | (((c >> sh) & 0xFFFFu) << 16);
        }
        unsigned int* dst = (unsigned int*)vt
            + ((size_t)((b * NHEADS + h) * HDIM + lane)) * (SEQ / 2)
            + ((s0 + w * 32) >> 1);
        #pragma unroll
        for (int j = 0; j < 4; ++j)
            *(v4u*)(dst + 4 * j) = (v4u){out[4*j], out[4*j+1], out[4*j+2], out[4*j+3]};
    }
}

// ---------------- main flash-attention kernel -------------------------------
__global__ __launch_bounds__(256, 4)
void fa_fwd(const float* __restrict__ qf, const unsigned short* __restrict__ kb,
            const unsigned short* __restrict__ vt, float* __restrict__ og)
{
    __shared__ __align__(16) unsigned short k_s[2][64 * 64];  // [kcol s][hd], swizzled
    __shared__ __align__(16) unsigned short v_s[2][64 * 64];  // [hd][kcol s], swizzled
    // LDS total = exactly 32 KB

    const int tid  = threadIdx.x;
    const int wave = tid >> 6;
    const int lane = tid & 63;
    const int hh   = lane >> 5;          // half-wave
    const int l32  = lane & 31;

    const int n  = (int)blockIdx.x;
    const int qtile = QTILES - 1 - (n >> 5);   // longest first; bh fastest (XCD spread)
    const int bh = n & 31;
    const int b = bh >> 4, h = bh & 15;
    const int qbase = qtile * BM;
    const int jmax  = 2 * qtile + 2;

    // DMA lane mapping: lane -> (local row = rbase + (lane>>3), slot lane&7);
    // source data-group = (lane&7) ^ fswz(local row) = (lane&7) ^ (lane>>3) ^ wave
    const int lrow  = lane >> 3;
    const int lcol8 = (lane & 7) ^ lrow ^ wave;
    // frag-read group xor term: fswz(mt*32 + l32) = (l32&7) ^ ((l32>>3)&3)
    const int fx = (l32 & 7) ^ ((l32 >> 3) & 3);

    // ---- stage Q (128x64, scaled, fp32 -> bf16) once through buf0 ----
    {
        const int krow = tid >> 2;                 // 0..63
        const int kc   = (tid & 3) * 16;
        const int sg0  = (2 * (tid & 3))     ^ fswz(krow);
        const int sg1  = (2 * (tid & 3) + 1) ^ fswz(krow);
        const float sc = 0.125f * 1.44269504088896340736f;
        #pragma unroll
        for (int half = 0; half < 2; ++half) {
            const float4* src = (const float4*)(qf +
                ((size_t)((b * SEQ + qbase + half * 64 + krow) * NHEADS + h)) * HDIM + kc);
            float4 f0 = src[0], f1 = src[1], f2 = src[2], f3 = src[3];
            unsigned short* dst = half ? &v_s[0][krow * 64] : &k_s[0][krow * 64];
            *(v4u*)&dst[sg0 * 8] = (v4u){pkbf(f0.x*sc, f0.y*sc), pkbf(f0.z*sc, f0.w*sc),
                                         pkbf(f1.x*sc, f1.y*sc), pkbf(f1.z*sc, f1.w*sc)};
            *(v4u*)&dst[sg1 * 8] = (v4u){pkbf(f2.x*sc, f2.y*sc), pkbf(f2.z*sc, f2.w*sc),
                                         pkbf(f3.x*sc, f3.y*sc), pkbf(f3.z*sc, f3.w*sc)};
        }
    }
    __syncthreads();
    v8s bq[4];   // lane holds Q[q = wave*32+l32][hd = 16c + hh*8 + j]
    {
        const int R = wave * 32 + l32;
        const unsigned short* qrow = (R < 64) ? &k_s[0][R * 64] : &v_s[0][(R - 64) * 64];
        #pragma unroll
        for (int c = 0; c < 4; ++c)
            bq[c] = *(const v8s*)&qrow[(((2*c + hh) ^ fswz(R & 63)) * 8)];
    }
    __syncthreads();   // Q reads done before tile-0 DMA overwrites buf0

    const unsigned short* kgb = kb + (size_t)b * SEQ * ROWSTR + (size_t)h * HDIM;
    const unsigned short* vgb = vt + (size_t)bh * HDIM * SEQ;

    // ---- K/V tile 0 ----
    #pragma unroll
    for (int i = 0; i < 2; ++i) {
        const int rbase = i * 32 + wave * 8;
        async16(kgb + (size_t)(rbase + lrow) * ROWSTR + lcol8 * 8, &k_s[0][rbase * 64]);
        async16(vgb + (size_t)(rbase + lrow) * SEQ    + lcol8 * 8, &v_s[0][rbase * 64]);
    }

    const v16f vzero = (v16f)(0.f);      // persistent C=0 operand
    v16f o_acc[2];
    o_acc[0] = (v16f)(0.f); o_acc[1] = (v16f)(0.f);
    float l_lane = 0.f;
    const int q_abs = qbase + wave * 32 + l32;

#if __has_builtin(__builtin_amdgcn_fdot2_f32_bf16)
    const v2bf ones2 = __builtin_bit_cast(v2bf, 0x3F803F80u);   // {1.0bf, 1.0bf}
#endif

    for (int jt = 0; jt < jmax; ++jt) {
        const int buf = jt & 1;
        __syncthreads();   // implicit vmcnt(0): tile jt resident; prior buf reads done

        if (jt + 1 < jmax) {   // prefetch jt+1; in flight across this iteration
            const int nb  = (jt + 1) & 1;
            const int kb2 = (jt + 1) * BN;
            #pragma unroll
            for (int i = 0; i < 2; ++i) {
                const int rbase = i * 32 + wave * 8;
                async16(kgb + (size_t)(kb2 + rbase + lrow) * ROWSTR + lcol8 * 8, &k_s[nb][rbase * 64]);
                async16(vgb + (size_t)(rbase + lrow) * SEQ + kb2    + lcol8 * 8, &v_s[nb][rbase * 64]);
            }
        }

        // ---- S^T = K Q^T : M=kcol(64, 2 tiles), N=q(32), K=hd(64, 4 chunks) ----
        v16f sacc[2];
        __builtin_amdgcn_s_setprio(1);
        #pragma unroll
        for (int mt = 0; mt < 2; ++mt) {
            const int r = mt * 32 + l32;   // k-col row in k_s
            {
                v8s ak = *(const v8s*)&k_s[buf][r * 64 + ((hh ^ fx) * 8)];
                sacc[mt] = __builtin_amdgcn_mfma_f32_32x32x16_bf16(ak, bq[0], vzero, 0, 0, 0);
            }
            #pragma unroll
            for (int c = 1; c < 4; ++c) {
                v8s ak = *(const v8s*)&k_s[buf][r * 64 + (((2*c + hh) ^ fx) * 8)];
                sacc[mt] = __builtin_amdgcn_mfma_f32_32x32x16_bf16(ak, bq[c], sacc[mt], 0, 0, 0);
            }
        }
        __builtin_amdgcn_s_setprio(0);

        // ---- softmax + PV, mt-phased: exp(mt1) [VALU] overlaps PV(c=0,1)
        //      [MFMA] since PV chunks c=0,1 consume only mt0's P. ----
        const bool masked = (jt >= jmax - 2);
        v8s pf4[4];

        auto exppack = [&](v16f& sc, v8s& d0, v8s& d1, int kofs) {
            #pragma unroll
            for (int r = 0; r < 16; ++r) {
                float pv = __builtin_amdgcn_exp2f(sc[r]);
                if (masked) {
                    const int k_abs = kofs + (r & 3) + 8 * (r >> 2) + 4 * hh;
                    pv = (k_abs > q_abs) ? 0.f : pv;
                }
                sc[r] = pv;
#if !__has_builtin(__builtin_amdgcn_fdot2_f32_bf16)
                l_lane += pv;
#endif
            }
            #pragma unroll
            for (int cc = 0; cc < 2; ++cc) {
                const unsigned lo0 = pkbf(sc[8*cc+0], sc[8*cc+1]);
                const unsigned lo1 = pkbf(sc[8*cc+2], sc[8*cc+3]);
                const unsigned hi0 = pkbf(sc[8*cc+4], sc[8*cc+5]);
                const unsigned hi1 = pkbf(sc[8*cc+6], sc[8*cc+7]);
#if __has_builtin(__builtin_amdgcn_fdot2_f32_bf16)
                // l-sum on packed bf16 P: matches the bf16 numerator rounding.
                l_lane = __builtin_amdgcn_fdot2_f32_bf16(__builtin_bit_cast(v2bf, lo0), ones2, l_lane, false);
                l_lane = __builtin_amdgcn_fdot2_f32_bf16(__builtin_bit_cast(v2bf, lo1), ones2, l_lane, false);
                l_lane = __builtin_amdgcn_fdot2_f32_bf16(__builtin_bit_cast(v2bf, hi0), ones2, l_lane, false);
                l_lane = __builtin_amdgcn_fdot2_f32_bf16(__builtin_bit_cast(v2bf, hi1), ones2, l_lane, false);
#endif
#if __has_builtin(__builtin_amdgcn_permlane32_swap)
                auto r0 = __builtin_amdgcn_permlane32_swap(lo0, hi0, false, false);
                auto r1 = __builtin_amdgcn_permlane32_swap(lo1, hi1, false, false);
                (cc ? d1 : d0) = __builtin_bit_cast(v8s, (v4u){r0[0], r1[0], r0[1], r1[1]});
#else
                const unsigned s0 = hh ? lo0 : hi0;   // send interleaved run
                const unsigned s1 = hh ? lo1 : hi1;
                const unsigned t0 = (unsigned)__shfl_xor((int)s0, 32, 64);
                const unsigned t1 = (unsigned)__shfl_xor((int)s1, 32, 64);
                v4u w;
                w.x = hh ? t0 : lo0;
                w.y = hh ? t1 : lo1;
                w.z = hh ? hi0 : t0;
                w.w = hh ? hi1 : t1;
                (cc ? d1 : d0) = __builtin_bit_cast(v8s, w);
#endif
            }
        };

        // phase A: P for mt0
        exppack(sacc[0], pf4[0], pf4[1], jt * 64);

        // PV half 1 (c = 0,1) -- consumes pf4[0..1] only
        __builtin_amdgcn_s_setprio(1);
        #pragma unroll
        for (int nt = 0; nt < 2; ++nt) {
            const int r = nt * 32 + l32;   // hd row in v_s
            #pragma unroll
            for (int c = 0; c < 2; ++c) {
                v8s bv = *(const v8s*)&v_s[buf][r * 64 + (((2*c + hh) ^ fx) * 8)];
                o_acc[nt] = __builtin_amdgcn_mfma_f32_32x32x16_bf16(pf4[c], bv, o_acc[nt], 0, 0, 0);
            }
        }
        __builtin_amdgcn_s_setprio(0);

        // phase B: P for mt1 (VALU; overlaps the PV half-1 MFMAs in flight)
        exppack(sacc[1], pf4[2], pf4[3], jt * 64 + 32);

        // PV half 2 (c = 2,3)
        __builtin_amdgcn_s_setprio(1);
        #pragma unroll
        for (int nt = 0; nt < 2; ++nt) {
            const int r = nt * 32 + l32;
            #pragma unroll
            for (int c = 2; c < 4; ++c) {
                v8s bv = *(const v8s*)&v_s[buf][r * 64 + (((2*c + hh) ^ fx) * 8)];
                o_acc[nt] = __builtin_amdgcn_mfma_f32_32x32x16_bf16(pf4[c], bv, o_acc[nt], 0, 0, 0);
            }
        }
        __builtin_amdgcn_s_setprio(0);
    }

    // ---- epilogue: l via wave shuffles (no LDS, no extra barrier) ----
    // lt = full row-sum for q = wave*32 + l32, valid in all 64 lanes.
    const float lt = l_lane + __shfl_xor(l_lane, 32);

    #pragma unroll
    for (int r = 0; r < 16; ++r) {
        const int q_local = (r & 3) + 8 * (r >> 2) + 4 * hh;
        const float inv_l = 1.0f / __shfl(lt, q_local, 32);   // within 32-lane group
        const int qrow = qbase + wave * 32 + q_local;
        float* dst = og + ((size_t)((b * SEQ + qrow) * NHEADS + h)) * HDIM + l32;
        dst[0]  = o_acc[0][r] * inv_l;
        dst[32] = o_acc[1][r] * inv_l;
    }
}

extern "C" void kernel_launch(void* const* d_in, const int* in_sizes, int n_in,
                              void* d_out, int out_size, void* d_ws, size_t ws_size,
                              hipStream_t stream) {
    const float* q = (const float*)d_in[0];
    const float* k = (const float*)d_in[1];
    const float* v = (const float*)d_in[2];
    float* out = (float*)d_out;

    const size_t TEN = (size_t)BATCH * NHEADS * SEQ * HDIM;  // 8.39M elems
    unsigned short* kbuf = (unsigned short*)d_ws;
    unsigned short* vbuf = kbuf + TEN;

    prep<<<2048, 256, 0, stream>>>(k, v, kbuf, vbuf);
    fa_fwd<<<QTILES * BH, 256, 0, stream>>>(q, kbuf, vbuf, out);
}